// Round 1
// baseline (410.984 us; speedup 1.0000x reference)
//
#include <hip/hip_runtime.h>
#include <hip/hip_bf16.h>
#include <stdint.h>

typedef __bf16 bf16_t;
typedef __attribute__((ext_vector_type(8))) __bf16 bf16x8;
typedef __attribute__((ext_vector_type(4))) float f32x4;

#define DIM_IN  4096
#define DIM_OUT 4096
#define DIM_S   1024
#define DIM_S2  2048
#define NROWS   8192   // B*T = 4*2048

typedef const __attribute__((address_space(1))) void gvoid_t;
typedef __attribute__((address_space(3))) void lvoid_t;

__device__ __forceinline__ float signf(float v) {
    return (v > 0.f) ? 1.f : ((v < 0.f) ? -1.f : 0.f);
}

// ---------------- prep kernels ----------------

// x fp32 [NROWS*DIM_IN] -> bf16
__global__ void cast_x_kernel(const float* __restrict__ x, bf16_t* __restrict__ xb) {
    int idx = blockIdx.x * blockDim.x + threadIdx.x;   // one per 8 elems
    const float4* p = reinterpret_cast<const float4*>(x) + (size_t)idx * 2;
    float4 a = p[0], b = p[1];
    bf16x8 o;
    o[0] = (bf16_t)a.x; o[1] = (bf16_t)a.y; o[2] = (bf16_t)a.z; o[3] = (bf16_t)a.w;
    o[4] = (bf16_t)b.x; o[5] = (bf16_t)b.y; o[6] = (bf16_t)b.z; o[7] = (bf16_t)b.w;
    reinterpret_cast<bf16x8*>(xb)[idx] = o;
}

// Vcat[s2][i] = v2[i]*sign(V[s2][i])  (s2<1024: branch 1, else branch R)
__global__ void build_vcat_kernel(const float* __restrict__ V, const float* __restrict__ v2,
                                  const float* __restrict__ V_R, const float* __restrict__ v2_R,
                                  bf16_t* __restrict__ out) {
    int idx = blockIdx.x * blockDim.x + threadIdx.x;   // 2048 * 512
    int s2 = idx >> 9;
    int i0 = (idx & 511) * 8;
    const float* src; const float* sc;
    if (s2 < DIM_S) { src = V   + (size_t)s2 * DIM_IN;          sc = v2;   }
    else            { src = V_R + (size_t)(s2 - DIM_S) * DIM_IN; sc = v2_R; }
    float4 a  = *reinterpret_cast<const float4*>(src + i0);
    float4 b  = *reinterpret_cast<const float4*>(src + i0 + 4);
    float4 sa = *reinterpret_cast<const float4*>(sc + i0);
    float4 sb = *reinterpret_cast<const float4*>(sc + i0 + 4);
    bf16x8 o;
    o[0] = (bf16_t)(signf(a.x) * sa.x); o[1] = (bf16_t)(signf(a.y) * sa.y);
    o[2] = (bf16_t)(signf(a.z) * sa.z); o[3] = (bf16_t)(signf(a.w) * sa.w);
    o[4] = (bf16_t)(signf(b.x) * sb.x); o[5] = (bf16_t)(signf(b.y) * sb.y);
    o[6] = (bf16_t)(signf(b.z) * sb.z); o[7] = (bf16_t)(signf(b.w) * sb.w);
    reinterpret_cast<bf16x8*>(out)[idx] = o;
}

// Wcat[j][s2] = u1[j]*v1[s2]*u2[s2]*sign(U[j][s2]) (s2<1024) else R-version
__global__ void build_wcat_kernel(const float* __restrict__ U, const float* __restrict__ v1,
                                  const float* __restrict__ u2, const float* __restrict__ u1,
                                  const float* __restrict__ U_R, const float* __restrict__ v1_R,
                                  const float* __restrict__ u2_R, const float* __restrict__ u1_R,
                                  bf16_t* __restrict__ out) {
    int idx = blockIdx.x * blockDim.x + threadIdx.x;   // 4096 * 256
    int j  = idx >> 8;
    int s0 = (idx & 255) * 8;      // 8-chunks never straddle the 1024 boundary
    const float* srcU; const float* sv1; const float* su2; float amp;
    if (s0 < DIM_S) { srcU = U   + (size_t)j * DIM_S + s0; sv1 = v1 + s0;   su2 = u2 + s0;   amp = u1[j];   }
    else { int s = s0 - DIM_S;
           srcU = U_R + (size_t)j * DIM_S + s;  sv1 = v1_R + s; su2 = u2_R + s; amp = u1_R[j]; }
    float4 a  = *reinterpret_cast<const float4*>(srcU);
    float4 b  = *reinterpret_cast<const float4*>(srcU + 4);
    float4 va = *reinterpret_cast<const float4*>(sv1);
    float4 vb = *reinterpret_cast<const float4*>(sv1 + 4);
    float4 ua = *reinterpret_cast<const float4*>(su2);
    float4 ub = *reinterpret_cast<const float4*>(su2 + 4);
    bf16x8 o;
    o[0] = (bf16_t)(amp * va.x * ua.x * signf(a.x));
    o[1] = (bf16_t)(amp * va.y * ua.y * signf(a.y));
    o[2] = (bf16_t)(amp * va.z * ua.z * signf(a.z));
    o[3] = (bf16_t)(amp * va.w * ua.w * signf(a.w));
    o[4] = (bf16_t)(amp * vb.x * ub.x * signf(b.x));
    o[5] = (bf16_t)(amp * vb.y * ub.y * signf(b.y));
    o[6] = (bf16_t)(amp * vb.z * ub.z * signf(b.z));
    o[7] = (bf16_t)(amp * vb.w * ub.w * signf(b.w));
    reinterpret_cast<bf16x8*>(out)[idx] = o;
}

// ---------------- GEMM: C[M][N] = A[M][K] @ B[N][K]^T ----------------
// m97 structure: 128x128 tile, BK=32, 4 waves (2x2), 16x16x32 bf16 MFMA,
// global_load_lds width=16, 2 barriers per K-step.
template<int N, int K, bool OUT_BF16>
__global__ __launch_bounds__(256) void gemm_bt_kernel(
        const bf16_t* __restrict__ A, const bf16_t* __restrict__ B,
        bf16_t* __restrict__ Cb, float* __restrict__ Cf,
        const float* __restrict__ bias) {
    __shared__ bf16_t sA[128 * 32];
    __shared__ bf16_t sB[128 * 32];
    const int tid  = threadIdx.x;
    const int wave = tid >> 6;
    const int lane = tid & 63;
    const int m0 = blockIdx.y * 128;
    const int n0 = blockIdx.x * 128;
    const int wr = wave >> 1, wc = wave & 1;

    f32x4 acc[4][4];
    #pragma unroll
    for (int m = 0; m < 4; ++m)
        #pragma unroll
        for (int n = 0; n < 4; ++n) acc[m][n] = (f32x4){0.f, 0.f, 0.f, 0.f};

    // staging: wave stages 32 rows of each tile (2 instrs of 16 rows each).
    // lane l -> row (l>>2), byte-in-row (l&3)*16  == LDS linear order.
    const char* gA = (const char*)A + ((size_t)(m0 + wave*32 + (lane >> 2)) * K) * 2 + (lane & 3) * 16;
    const char* gB = (const char*)B + ((size_t)(n0 + wave*32 + (lane >> 2)) * K) * 2 + (lane & 3) * 16;
    bf16_t* lA0 = sA + wave * 1024;
    bf16_t* lA1 = sA + wave * 1024 + 512;
    bf16_t* lB0 = sB + wave * 1024;
    bf16_t* lB1 = sB + wave * 1024 + 512;

    const int fr = lane & 15;          // fragment row (A) / col-row (B)
    const int fk = (lane >> 4) * 8;    // fragment k offset

    for (int kt = 0; kt < K; kt += 32) {
        __syncthreads();   // previous compute done before overwrite
        __builtin_amdgcn_global_load_lds((gvoid_t*)(gA),          (lvoid_t*)lA0, 16, 0, 0);
        __builtin_amdgcn_global_load_lds((gvoid_t*)(gA + 32 * K), (lvoid_t*)lA1, 16, 0, 0);
        __builtin_amdgcn_global_load_lds((gvoid_t*)(gB),          (lvoid_t*)lB0, 16, 0, 0);
        __builtin_amdgcn_global_load_lds((gvoid_t*)(gB + 32 * K), (lvoid_t*)lB1, 16, 0, 0);
        gA += 64; gB += 64;            // advance 32 bf16 in K
        __syncthreads();               // drains vmcnt(0) -> tiles ready

        bf16x8 af[4], bf[4];
        #pragma unroll
        for (int m = 0; m < 4; ++m)
            af[m] = *reinterpret_cast<const bf16x8*>(sA + (wr*64 + m*16 + fr) * 32 + fk);
        #pragma unroll
        for (int n = 0; n < 4; ++n)
            bf[n] = *reinterpret_cast<const bf16x8*>(sB + (wc*64 + n*16 + fr) * 32 + fk);
        #pragma unroll
        for (int m = 0; m < 4; ++m)
            #pragma unroll
            for (int n = 0; n < 4; ++n)
                acc[m][n] = __builtin_amdgcn_mfma_f32_16x16x32_bf16(af[m], bf[n], acc[m][n], 0, 0, 0);
    }

    // epilogue: C/D layout col=lane&15, row=(lane>>4)*4+reg (m89-verified)
    const int cr = (lane >> 4) * 4;
    const int cc = lane & 15;
    #pragma unroll
    for (int m = 0; m < 4; ++m) {
        #pragma unroll
        for (int n = 0; n < 4; ++n) {
            int row = m0 + wr*64 + m*16 + cr;
            int col = n0 + wc*64 + n*16 + cc;
            if (OUT_BF16) {
                #pragma unroll
                for (int j = 0; j < 4; ++j)
                    Cb[(size_t)(row + j) * N + col] = (bf16_t)acc[m][n][j];
            } else {
                float bv = bias[col];
                #pragma unroll
                for (int j = 0; j < 4; ++j)
                    Cf[(size_t)(row + j) * N + col] = acc[m][n][j] + bv;
            }
        }
    }
}

// ---------------- launch ----------------
extern "C" void kernel_launch(void* const* d_in, const int* in_sizes, int n_in,
                              void* d_out, int out_size, void* d_ws, size_t ws_size,
                              hipStream_t stream) {
    const float* x    = (const float*)d_in[0];
    const float* V    = (const float*)d_in[1];
    const float* U    = (const float*)d_in[2];
    const float* v2   = (const float*)d_in[3];
    const float* v1   = (const float*)d_in[4];
    const float* u2   = (const float*)d_in[5];
    const float* u1   = (const float*)d_in[6];
    const float* V_R  = (const float*)d_in[7];
    const float* U_R  = (const float*)d_in[8];
    const float* v2_R = (const float*)d_in[9];
    const float* v1_R = (const float*)d_in[10];
    const float* u2_R = (const float*)d_in[11];
    const float* u1_R = (const float*)d_in[12];
    const float* bias = (const float*)d_in[13];
    float* out = (float*)d_out;

    char* ws = (char*)d_ws;
    bf16_t* Xb   = (bf16_t*)(ws);                                  // 64 MB: [8192][4096]
    bf16_t* Vcat = (bf16_t*)(ws + (size_t)64  * 1024 * 1024);      // 16 MB: [2048][4096]
    bf16_t* Wcat = (bf16_t*)(ws + (size_t)80  * 1024 * 1024);      // 16 MB: [4096][2048]
    bf16_t* Hb   = (bf16_t*)(ws + (size_t)96  * 1024 * 1024);      // 32 MB: [8192][2048]

    cast_x_kernel   <<<16384, 256, 0, stream>>>(x, Xb);
    build_vcat_kernel<<<4096, 256, 0, stream>>>(V, v2, V_R, v2_R, Vcat);
    build_wcat_kernel<<<4096, 256, 0, stream>>>(U, v1, u2, u1, U_R, v1_R, u2_R, u1_R, Wcat);

    // GEMM1: H[8192][2048] = Xb @ Vcat^T   (K=4096)
    gemm_bt_kernel<DIM_S2, DIM_IN, true>
        <<<dim3(DIM_S2 / 128, NROWS / 128), 256, 0, stream>>>(Xb, Vcat, Hb, nullptr, nullptr);
    // GEMM2: out[8192][4096] = Hb @ Wcat^T + bias   (K=2048)
    gemm_bt_kernel<DIM_OUT, DIM_S2, false>
        <<<dim3(DIM_OUT / 128, NROWS / 128), 256, 0, stream>>>(Hb, Wcat, nullptr, out, bias);
}

// Round 2
// 312.409 us; speedup vs baseline: 1.3155x; 1.3155x over previous
//
#include <hip/hip_runtime.h>
#include <hip/hip_bf16.h>
#include <stdint.h>

typedef __bf16 bf16_t;
typedef __attribute__((ext_vector_type(8))) __bf16 bf16x8;
typedef __attribute__((ext_vector_type(4))) float f32x4;

#define DIM_IN  4096
#define DIM_OUT 4096
#define DIM_S   1024
#define DIM_S2  2048
#define NROWS   8192   // B*T = 4*2048

typedef const __attribute__((address_space(1))) void gvoid_t;
typedef __attribute__((address_space(3))) void lvoid_t;

__device__ __forceinline__ float signf(float v) {
    return (v > 0.f) ? 1.f : ((v < 0.f) ? -1.f : 0.f);
}

// ---------------- prep kernels ----------------

__global__ void cast_x_kernel(const float* __restrict__ x, bf16_t* __restrict__ xb) {
    int idx = blockIdx.x * blockDim.x + threadIdx.x;
    const float4* p = reinterpret_cast<const float4*>(x) + (size_t)idx * 2;
    float4 a = p[0], b = p[1];
    bf16x8 o;
    o[0] = (bf16_t)a.x; o[1] = (bf16_t)a.y; o[2] = (bf16_t)a.z; o[3] = (bf16_t)a.w;
    o[4] = (bf16_t)b.x; o[5] = (bf16_t)b.y; o[6] = (bf16_t)b.z; o[7] = (bf16_t)b.w;
    reinterpret_cast<bf16x8*>(xb)[idx] = o;
}

__global__ void build_vcat_kernel(const float* __restrict__ V, const float* __restrict__ v2,
                                  const float* __restrict__ V_R, const float* __restrict__ v2_R,
                                  bf16_t* __restrict__ out) {
    int idx = blockIdx.x * blockDim.x + threadIdx.x;
    int s2 = idx >> 9;
    int i0 = (idx & 511) * 8;
    const float* src; const float* sc;
    if (s2 < DIM_S) { src = V   + (size_t)s2 * DIM_IN;           sc = v2;   }
    else            { src = V_R + (size_t)(s2 - DIM_S) * DIM_IN; sc = v2_R; }
    float4 a  = *reinterpret_cast<const float4*>(src + i0);
    float4 b  = *reinterpret_cast<const float4*>(src + i0 + 4);
    float4 sa = *reinterpret_cast<const float4*>(sc + i0);
    float4 sb = *reinterpret_cast<const float4*>(sc + i0 + 4);
    bf16x8 o;
    o[0] = (bf16_t)(signf(a.x) * sa.x); o[1] = (bf16_t)(signf(a.y) * sa.y);
    o[2] = (bf16_t)(signf(a.z) * sa.z); o[3] = (bf16_t)(signf(a.w) * sa.w);
    o[4] = (bf16_t)(signf(b.x) * sb.x); o[5] = (bf16_t)(signf(b.y) * sb.y);
    o[6] = (bf16_t)(signf(b.z) * sb.z); o[7] = (bf16_t)(signf(b.w) * sb.w);
    reinterpret_cast<bf16x8*>(out)[idx] = o;
}

__global__ void build_wcat_kernel(const float* __restrict__ U, const float* __restrict__ v1,
                                  const float* __restrict__ u2, const float* __restrict__ u1,
                                  const float* __restrict__ U_R, const float* __restrict__ v1_R,
                                  const float* __restrict__ u2_R, const float* __restrict__ u1_R,
                                  bf16_t* __restrict__ out) {
    int idx = blockIdx.x * blockDim.x + threadIdx.x;
    int j  = idx >> 8;
    int s0 = (idx & 255) * 8;
    const float* srcU; const float* sv1; const float* su2; float amp;
    if (s0 < DIM_S) { srcU = U   + (size_t)j * DIM_S + s0; sv1 = v1 + s0;   su2 = u2 + s0;   amp = u1[j];   }
    else { int s = s0 - DIM_S;
           srcU = U_R + (size_t)j * DIM_S + s;  sv1 = v1_R + s; su2 = u2_R + s; amp = u1_R[j]; }
    float4 a  = *reinterpret_cast<const float4*>(srcU);
    float4 b  = *reinterpret_cast<const float4*>(srcU + 4);
    float4 va = *reinterpret_cast<const float4*>(sv1);
    float4 vb = *reinterpret_cast<const float4*>(sv1 + 4);
    float4 ua = *reinterpret_cast<const float4*>(su2);
    float4 ub = *reinterpret_cast<const float4*>(su2 + 4);
    bf16x8 o;
    o[0] = (bf16_t)(amp * va.x * ua.x * signf(a.x));
    o[1] = (bf16_t)(amp * va.y * ua.y * signf(a.y));
    o[2] = (bf16_t)(amp * va.z * ua.z * signf(a.z));
    o[3] = (bf16_t)(amp * va.w * ua.w * signf(a.w));
    o[4] = (bf16_t)(amp * vb.x * ub.x * signf(b.x));
    o[5] = (bf16_t)(amp * vb.y * ub.y * signf(b.y));
    o[6] = (bf16_t)(amp * vb.z * ub.z * signf(b.z));
    o[7] = (bf16_t)(amp * vb.w * ub.w * signf(b.w));
    reinterpret_cast<bf16x8*>(out)[idx] = o;
}

// ---------------- 256x256 8-phase GEMM: C[M][N] = A[M][K] @ B[N][K]^T ----------------
// 512 thr = 8 waves (2Mx4N), per-wave out 128x64, BK=64 as 2x [256][32] k-half blocks.
// LDS 128 KiB: A: buf*32768 + kh*16384 (64KB) | B at +65536 (64KB).
// Swizzle (T2): byte ^= ((byte>>7)&3)<<4 within each 16KB block; applied to the
// global SOURCE of global_load_lds (linear LDS dest) and to ds_read offsets.

#define VMCNT(n) do { asm volatile("s_waitcnt vmcnt(" #n ")" ::: "memory"); \
                      __builtin_amdgcn_sched_barrier(0); } while (0)

template<int N, int K, bool OUT_BF16>
__global__ __launch_bounds__(512, 2) void gemm256_kernel(
        const bf16_t* __restrict__ A, const bf16_t* __restrict__ B,
        bf16_t* __restrict__ Cb, float* __restrict__ Cf,
        const float* __restrict__ bias) {
    extern __shared__ char lds[];
    constexpr int NT = K / 64;
    const int tid  = threadIdx.x;
    const int wave = tid >> 6;
    const int lane = tid & 63;
    const int wr = wave >> 2;    // 0..1
    const int wc = wave & 3;     // 0..3

    // T1: XCD-aware bijective swizzle (nwg % 8 == 0 for both GEMMs)
    const int nwg  = gridDim.x;
    const int orig = blockIdx.x;
    const int swz  = (orig & 7) * (nwg >> 3) + (orig >> 3);
    constexpr int NTX = N / 256;
    const int n0 = (swz % NTX) * 256;
    const int m0 = (swz / NTX) * 256;

    char* ldsA = lds;
    char* ldsB = lds + 65536;

    // staging: per wave-instr j: linear LDS off = j*8192 + wave*1024 + lane*16;
    // global source pre-inverse-swizzled so LDS[off] = G[off ^ (((off>>7)&3)<<4)]
    const char* gA[2]; const char* gB[2];
#pragma unroll
    for (int j = 0; j < 2; ++j) {
        int off = j * 8192 + wave * 1024 + lane * 16;
        int lg  = off ^ (((off >> 7) & 3) << 4);
        int row = lg >> 6;
        int cb  = lg & 63;
        gA[j] = (const char*)A + (size_t)(m0 + row) * (K * 2) + cb;
        gB[j] = (const char*)B + (size_t)(n0 + row) * (K * 2) + cb;
    }

#define STAGE_A(t, kh) do { \
    int _lo = (((t) & 1) << 15) + ((kh) << 14) + (wave << 10); \
    int _ga = (t) * 128 + (kh) * 64; \
    __builtin_amdgcn_global_load_lds((gvoid_t*)(gA[0] + _ga), (lvoid_t*)(ldsA + _lo), 16, 0, 0); \
    __builtin_amdgcn_global_load_lds((gvoid_t*)(gA[1] + _ga), (lvoid_t*)(ldsA + _lo + 8192), 16, 0, 0); \
} while (0)
#define STAGE_B(t, kh) do { \
    int _lo = (((t) & 1) << 15) + ((kh) << 14) + (wave << 10); \
    int _ga = (t) * 128 + (kh) * 64; \
    __builtin_amdgcn_global_load_lds((gvoid_t*)(gB[0] + _ga), (lvoid_t*)(ldsB + _lo), 16, 0, 0); \
    __builtin_amdgcn_global_load_lds((gvoid_t*)(gB[1] + _ga), (lvoid_t*)(ldsB + _lo + 8192), 16, 0, 0); \
} while (0)

    // prologue: issue 6 half-tiles IN THIS ORDER (vmcnt ledger depends on it)
    STAGE_A(0, 0); STAGE_B(0, 0);
    STAGE_A(0, 1); STAGE_B(0, 1);
    STAGE_A(1, 0); STAGE_B(1, 0);

    // swizzled ds_read offsets within a 16KB block
    int aoff[8], boff[4];
#pragma unroll
    for (int m = 0; m < 8; ++m) {
        int row = wr * 128 + m * 16 + (lane & 15);
        int off = row * 64 + ((lane >> 4) << 4);
        aoff[m] = off ^ (((off >> 7) & 3) << 4);
    }
#pragma unroll
    for (int n = 0; n < 4; ++n) {
        int row = wc * 64 + n * 16 + (lane & 15);
        int off = row * 64 + ((lane >> 4) << 4);
        boff[n] = off ^ (((off >> 7) & 3) << 4);
    }

    f32x4 acc[8][4];
#pragma unroll
    for (int m = 0; m < 8; ++m)
#pragma unroll
        for (int n = 0; n < 4; ++n)
            acc[m][n] = (f32x4){0.f, 0.f, 0.f, 0.f};

    bf16x8 bfr[4];

    VMCNT(8);                       // A(0,0),B(0,0) landed; 4 half-tiles in flight
    __builtin_amdgcn_s_barrier();

// phase: {ds_read frags; issue 1 half-tile; barrier; lgkmcnt(0); 16 MFMA; [vmcnt]; barrier}
#define PHASE(mh, kh, LOADB, STG, VMS) do { \
    const int _sb = ((t & 1) << 15) + ((kh) << 14); \
    bf16x8 _af[4]; \
    _Pragma("unroll") \
    for (int mi = 0; mi < 4; ++mi) \
        _af[mi] = *(const bf16x8*)(ldsA + _sb + aoff[(mh) * 4 + mi]); \
    if (LOADB) { \
        _Pragma("unroll") \
        for (int n = 0; n < 4; ++n) \
            bfr[n] = *(const bf16x8*)(ldsB + _sb + boff[n]); \
    } \
    STG; \
    __builtin_amdgcn_s_barrier(); \
    asm volatile("s_waitcnt lgkmcnt(0)" ::: "memory"); \
    __builtin_amdgcn_sched_barrier(0); \
    __builtin_amdgcn_s_setprio(1); \
    _Pragma("unroll") \
    for (int mi = 0; mi < 4; ++mi) \
        _Pragma("unroll") \
        for (int n = 0; n < 4; ++n) \
            acc[(mh) * 4 + mi][n] = __builtin_amdgcn_mfma_f32_16x16x32_bf16( \
                _af[mi], bfr[n], acc[(mh) * 4 + mi][n], 0, 0, 0); \
    __builtin_amdgcn_s_setprio(0); \
    VMS; \
    __builtin_amdgcn_s_barrier(); \
} while (0)

    for (int t = 0; t < NT; ++t) {
        const bool i1 = (t + 1 < NT);
        const bool i2 = (t + 2 < NT);
        // p0: (m-half0, k-half0); issue A(t+1, kh1) -> buf^1 (its last reader was t-1 p3)
        PHASE(0, 0, true,  { if (i1) STAGE_A(t + 1, 1); }, {});
        // p1: (m-half1, k-half0); issue B(t+1, kh1); end: drain A/B(t,kh1) (8 issued after)
        PHASE(1, 0, false, { if (i1) STAGE_B(t + 1, 1); },
              { if (i1) VMCNT(8); else VMCNT(0); });
        // p2: (m-half0, k-half1); issue A(t+2, kh0) -> buf (kh0 region consumed at p0/p1)
        PHASE(0, 1, true,  { if (i2) STAGE_A(t + 2, 0); }, {});
        // p3: (m-half1, k-half1); issue B(t+2, kh0); end: drain A/B(t+1,kh0)
        PHASE(1, 1, false, { if (i2) STAGE_B(t + 2, 0); },
              { if (i2) VMCNT(8); else VMCNT(4); });
    }

#undef PHASE
#undef STAGE_A
#undef STAGE_B

    // epilogue: C/D layout col=lane&15, row=(lane>>4)*4+reg (m89-verified)
    const int cr = (lane >> 4) << 2;
    const int cc = lane & 15;
#pragma unroll
    for (int m = 0; m < 8; ++m) {
        const int row = m0 + wr * 128 + m * 16 + cr;
#pragma unroll
        for (int n = 0; n < 4; ++n) {
            const int col = n0 + wc * 64 + n * 16 + cc;
            if (OUT_BF16) {
#pragma unroll
                for (int j = 0; j < 4; ++j)
                    Cb[(size_t)(row + j) * N + col] = (bf16_t)acc[m][n][j];
            } else {
                const float bv = bias[col];
#pragma unroll
                for (int j = 0; j < 4; ++j)
                    Cf[(size_t)(row + j) * N + col] = acc[m][n][j] + bv;
            }
        }
    }
}

// ---------------- launch ----------------
extern "C" void kernel_launch(void* const* d_in, const int* in_sizes, int n_in,
                              void* d_out, int out_size, void* d_ws, size_t ws_size,
                              hipStream_t stream) {
    const float* x    = (const float*)d_in[0];
    const float* V    = (const float*)d_in[1];
    const float* U    = (const float*)d_in[2];
    const float* v2   = (const float*)d_in[3];
    const float* v1   = (const float*)d_in[4];
    const float* u2   = (const float*)d_in[5];
    const float* u1   = (const float*)d_in[6];
    const float* V_R  = (const float*)d_in[7];
    const float* U_R  = (const float*)d_in[8];
    const float* v2_R = (const float*)d_in[9];
    const float* v1_R = (const float*)d_in[10];
    const float* u2_R = (const float*)d_in[11];
    const float* u1_R = (const float*)d_in[12];
    const float* bias = (const float*)d_in[13];
    float* out = (float*)d_out;

    char* ws = (char*)d_ws;
    bf16_t* Xb   = (bf16_t*)(ws);                                  // 64 MB: [8192][4096]
    bf16_t* Vcat = (bf16_t*)(ws + (size_t)64  * 1024 * 1024);      // 16 MB: [2048][4096]
    bf16_t* Wcat = (bf16_t*)(ws + (size_t)80  * 1024 * 1024);      // 16 MB: [4096][2048]
    bf16_t* Hb   = (bf16_t*)(ws + (size_t)96  * 1024 * 1024);      // 32 MB: [8192][2048]

    // 128 KiB dynamic LDS opt-in (idempotent, host-side, capture-safe)
    (void)hipFuncSetAttribute((const void*)gemm256_kernel<DIM_S2, DIM_IN, true>,
                              hipFuncAttributeMaxDynamicSharedMemorySize, 131072);
    (void)hipFuncSetAttribute((const void*)gemm256_kernel<DIM_OUT, DIM_S2, false>,
                              hipFuncAttributeMaxDynamicSharedMemorySize, 131072);

    cast_x_kernel    <<<16384, 256, 0, stream>>>(x, Xb);
    build_vcat_kernel<<<4096, 256, 0, stream>>>(V, v2, V_R, v2_R, Vcat);
    build_wcat_kernel<<<4096, 256, 0, stream>>>(U, v1, u2, u1, U_R, v1_R, u2_R, u1_R, Wcat);

    // GEMM1: H[8192][2048] = Xb @ Vcat^T   (K=4096), grid 8x32=256
    gemm256_kernel<DIM_S2, DIM_IN, true>
        <<<(DIM_S2 / 256) * (NROWS / 256), 512, 131072, stream>>>(Xb, Vcat, Hb, nullptr, nullptr);
    // GEMM2: out[8192][4096] = Hb @ Wcat^T + bias   (K=2048), grid 16x32=512
    gemm256_kernel<DIM_OUT, DIM_S2, false>
        <<<(DIM_OUT / 256) * (NROWS / 256), 512, 131072, stream>>>(Hb, Wcat, nullptr, out, bias);
}

// Round 3
// 309.223 us; speedup vs baseline: 1.3291x; 1.0103x over previous
//
#include <hip/hip_runtime.h>
#include <hip/hip_bf16.h>
#include <stdint.h>

typedef __bf16 bf16_t;
typedef __attribute__((ext_vector_type(8))) __bf16 bf16x8;
typedef __attribute__((ext_vector_type(4))) float f32x4;

#define DIM_IN  4096
#define DIM_OUT 4096
#define DIM_S   1024
#define DIM_S2  2048
#define NROWS   8192   // B*T = 4*2048

typedef const __attribute__((address_space(1))) void gvoid_t;
typedef __attribute__((address_space(3))) void lvoid_t;

__device__ __forceinline__ float signf(float v) {
    return (v > 0.f) ? 1.f : ((v < 0.f) ? -1.f : 0.f);
}

// ---------------- prep kernels ----------------

__global__ void cast_x_kernel(const float* __restrict__ x, bf16_t* __restrict__ xb) {
    int idx = blockIdx.x * blockDim.x + threadIdx.x;
    const float4* p = reinterpret_cast<const float4*>(x) + (size_t)idx * 2;
    float4 a = p[0], b = p[1];
    bf16x8 o;
    o[0] = (bf16_t)a.x; o[1] = (bf16_t)a.y; o[2] = (bf16_t)a.z; o[3] = (bf16_t)a.w;
    o[4] = (bf16_t)b.x; o[5] = (bf16_t)b.y; o[6] = (bf16_t)b.z; o[7] = (bf16_t)b.w;
    reinterpret_cast<bf16x8*>(xb)[idx] = o;
}

__global__ void build_vcat_kernel(const float* __restrict__ V, const float* __restrict__ v2,
                                  const float* __restrict__ V_R, const float* __restrict__ v2_R,
                                  bf16_t* __restrict__ out) {
    int idx = blockIdx.x * blockDim.x + threadIdx.x;
    int s2 = idx >> 9;
    int i0 = (idx & 511) * 8;
    const float* src; const float* sc;
    if (s2 < DIM_S) { src = V   + (size_t)s2 * DIM_IN;           sc = v2;   }
    else            { src = V_R + (size_t)(s2 - DIM_S) * DIM_IN; sc = v2_R; }
    float4 a  = *reinterpret_cast<const float4*>(src + i0);
    float4 b  = *reinterpret_cast<const float4*>(src + i0 + 4);
    float4 sa = *reinterpret_cast<const float4*>(sc + i0);
    float4 sb = *reinterpret_cast<const float4*>(sc + i0 + 4);
    bf16x8 o;
    o[0] = (bf16_t)(signf(a.x) * sa.x); o[1] = (bf16_t)(signf(a.y) * sa.y);
    o[2] = (bf16_t)(signf(a.z) * sa.z); o[3] = (bf16_t)(signf(a.w) * sa.w);
    o[4] = (bf16_t)(signf(b.x) * sb.x); o[5] = (bf16_t)(signf(b.y) * sb.y);
    o[6] = (bf16_t)(signf(b.z) * sb.z); o[7] = (bf16_t)(signf(b.w) * sb.w);
    reinterpret_cast<bf16x8*>(out)[idx] = o;
}

__global__ void build_wcat_kernel(const float* __restrict__ U, const float* __restrict__ v1,
                                  const float* __restrict__ u2, const float* __restrict__ u1,
                                  const float* __restrict__ U_R, const float* __restrict__ v1_R,
                                  const float* __restrict__ u2_R, const float* __restrict__ u1_R,
                                  bf16_t* __restrict__ out) {
    int idx = blockIdx.x * blockDim.x + threadIdx.x;
    int j  = idx >> 8;
    int s0 = (idx & 255) * 8;
    const float* srcU; const float* sv1; const float* su2; float amp;
    if (s0 < DIM_S) { srcU = U   + (size_t)j * DIM_S + s0; sv1 = v1 + s0;   su2 = u2 + s0;   amp = u1[j];   }
    else { int s = s0 - DIM_S;
           srcU = U_R + (size_t)j * DIM_S + s;  sv1 = v1_R + s; su2 = u2_R + s; amp = u1_R[j]; }
    float4 a  = *reinterpret_cast<const float4*>(srcU);
    float4 b  = *reinterpret_cast<const float4*>(srcU + 4);
    float4 va = *reinterpret_cast<const float4*>(sv1);
    float4 vb = *reinterpret_cast<const float4*>(sv1 + 4);
    float4 ua = *reinterpret_cast<const float4*>(su2);
    float4 ub = *reinterpret_cast<const float4*>(su2 + 4);
    bf16x8 o;
    o[0] = (bf16_t)(amp * va.x * ua.x * signf(a.x));
    o[1] = (bf16_t)(amp * va.y * ua.y * signf(a.y));
    o[2] = (bf16_t)(amp * va.z * ua.z * signf(a.z));
    o[3] = (bf16_t)(amp * va.w * ua.w * signf(a.w));
    o[4] = (bf16_t)(amp * vb.x * ub.x * signf(b.x));
    o[5] = (bf16_t)(amp * vb.y * ub.y * signf(b.y));
    o[6] = (bf16_t)(amp * vb.z * ub.z * signf(b.z));
    o[7] = (bf16_t)(amp * vb.w * ub.w * signf(b.w));
    reinterpret_cast<bf16x8*>(out)[idx] = o;
}

// ---------------- 256x256 pipelined 8-phase GEMM: C = A @ B^T ----------------
// 512 thr = 8 waves (2Mx4N), per-wave out 128x64, BK=64 as 2x [256][32] k-half
// blocks. LDS 128 KiB. T2 swizzle: byte ^= ((byte>>7)&3)<<4, applied to the
// global SOURCE (linear LDS dest) and to ds_read base addresses (XOR bits are
// invariant under the +1024B frag step, so one swizzled base + imm offsets).
// NEW (r3): fragment ds_reads issued ONE PHASE EARLY; counted lgkmcnt leaves
// this phase's reads in flight so MFMA overlaps the LDS transfer.

#define VMCNT(n) do { asm volatile("s_waitcnt vmcnt(" #n ")" ::: "memory"); \
                      __builtin_amdgcn_sched_barrier(0); } while (0)
#define LGKM(n)  do { asm volatile("s_waitcnt lgkmcnt(" #n ")" ::: "memory"); \
                      __builtin_amdgcn_sched_barrier(0); } while (0)

template<int N, int K, bool OUT_BF16>
__global__ __launch_bounds__(512, 2) void gemm256_kernel(
        const bf16_t* __restrict__ A, const bf16_t* __restrict__ B,
        bf16_t* __restrict__ Cb, float* __restrict__ Cf,
        const float* __restrict__ bias) {
    extern __shared__ char lds[];
    constexpr int NT = K / 64;
    static_assert(NT >= 4, "K too small");
    const int tid  = threadIdx.x;
    const int wave = tid >> 6;
    const int lane = tid & 63;
    const int wr = wave >> 2;    // 0..1
    const int wc = wave & 3;     // 0..3

    // T1: XCD-aware bijective swizzle (nwg % 8 == 0 for both GEMMs)
    const int nwg  = gridDim.x;
    const int orig = blockIdx.x;
    const int swz  = (orig & 7) * (nwg >> 3) + (orig >> 3);
    constexpr int NTX = N / 256;
    const int n0 = (swz % NTX) * 256;
    const int m0 = (swz / NTX) * 256;

    char* ldsA = lds;
    char* ldsB = lds + 65536;

    // staging source pointers (pre-inverse-swizzled, LDS dest linear)
    const char* gA[2]; const char* gB[2];
#pragma unroll
    for (int j = 0; j < 2; ++j) {
        int off = j * 8192 + wave * 1024 + lane * 16;
        int lg  = off ^ (((off >> 7) & 3) << 4);
        int row = lg >> 6;
        int cb  = lg & 63;
        gA[j] = (const char*)A + (size_t)(m0 + row) * (K * 2) + cb;
        gB[j] = (const char*)B + (size_t)(n0 + row) * (K * 2) + cb;
    }

#define STAGE_A(t, kh) do { \
    int _lo = (((t) & 1) << 15) + ((kh) << 14) + (wave << 10); \
    int _ga = (t) * 128 + (kh) * 64; \
    __builtin_amdgcn_global_load_lds((gvoid_t*)(gA[0] + _ga), (lvoid_t*)(ldsA + _lo), 16, 0, 0); \
    __builtin_amdgcn_global_load_lds((gvoid_t*)(gA[1] + _ga), (lvoid_t*)(ldsA + _lo + 8192), 16, 0, 0); \
} while (0)
#define STAGE_B(t, kh) do { \
    int _lo = (((t) & 1) << 15) + ((kh) << 14) + (wave << 10); \
    int _ga = (t) * 128 + (kh) * 64; \
    __builtin_amdgcn_global_load_lds((gvoid_t*)(gB[0] + _ga), (lvoid_t*)(ldsB + _lo), 16, 0, 0); \
    __builtin_amdgcn_global_load_lds((gvoid_t*)(gB[1] + _ga), (lvoid_t*)(ldsB + _lo + 8192), 16, 0, 0); \
} while (0)

    // swizzled ds_read BASE addresses: frag step (+1024B) and kh/buf bits are
    // above the XOR source bits (7-8), so one base + imm offset suffices.
    int abase, bbase;
    {
        int offA = (wr * 128 + (lane & 15)) * 64 + ((lane >> 4) << 4);
        abase = offA ^ (((offA >> 7) & 3) << 4);
        int offB = (wc * 64 + (lane & 15)) * 64 + ((lane >> 4) << 4);
        bbase = offB ^ (((offB >> 7) & 3) << 4);
    }

    f32x4 acc[8][4];
#pragma unroll
    for (int m = 0; m < 8; ++m)
#pragma unroll
        for (int n = 0; n < 4; ++n)
            acc[m][n] = (f32x4){0.f, 0.f, 0.f, 0.f};

    bf16x8 af0[4], af1[4], bf0[4], bf1[4];

#define RD_A4(dst, mh, kh, t_) do { \
    const int _sb = (((t_) & 1) << 15) + ((kh) << 14) + abase + (mh) * 4096; \
    _Pragma("unroll") \
    for (int mi = 0; mi < 4; ++mi) \
        dst[mi] = *(const bf16x8*)(ldsA + _sb + mi * 1024); \
} while (0)
#define RD_B4(dst, kh, t_) do { \
    const int _sb = (((t_) & 1) << 15) + ((kh) << 14) + bbase; \
    _Pragma("unroll") \
    for (int ni = 0; ni < 4; ++ni) \
        dst[ni] = *(const bf16x8*)(ldsB + _sb + ni * 1024); \
} while (0)
#define MFMA16(mh, AF, BF) do { \
    __builtin_amdgcn_s_setprio(1); \
    _Pragma("unroll") \
    for (int mi = 0; mi < 4; ++mi) \
        _Pragma("unroll") \
        for (int n = 0; n < 4; ++n) \
            acc[(mh) * 4 + mi][n] = __builtin_amdgcn_mfma_f32_16x16x32_bf16( \
                AF[mi], BF[n], acc[(mh) * 4 + mi][n], 0, 0, 0); \
    __builtin_amdgcn_s_setprio(0); \
} while (0)

    // prologue: 6 half-tiles; drain first K-half; initial frag reads
    STAGE_A(0, 0); STAGE_B(0, 0);
    STAGE_A(0, 1); STAGE_B(0, 1);
    STAGE_A(1, 0); STAGE_B(1, 0);
    VMCNT(8);                       // A(0,0),B(0,0) landed
    __builtin_amdgcn_s_barrier();
    RD_A4(af0, 0, 0, 0); RD_B4(bf0, 0, 0);   // frags for t0 p0

// One K-tile = 4 phases. Phase p: {issue p+1's frag reads; issue 1 half-tile
// stage; barrier; counted lgkm (leave this phase's reads in flight); 16 MFMA;
// [counted vmcnt]; barrier}. Ledger (steady state, I1=I2=true):
//  p0 end VMCNT(6): drains A(t,1),B(t,1)   -> kh1 readable at p1/p2
//  p2 end VMCNT(6): drains A(t+1,0),B(t+1,0) -> next-t kh0 readable at p3
#define KTILE(t_, I1, I2) do { \
    /* p0 */ \
    RD_A4(af1, 1, 0, t_); \
    if (I1) STAGE_A((t_) + 1, 1); \
    __builtin_amdgcn_s_barrier(); \
    LGKM(4); \
    MFMA16(0, af0, bf0); \
    if (I1) { VMCNT(6); } else { VMCNT(0); } \
    __builtin_amdgcn_s_barrier(); \
    /* p1 */ \
    RD_A4(af0, 0, 1, t_); RD_B4(bf1, 1, t_); \
    if (I1) STAGE_B((t_) + 1, 1); \
    __builtin_amdgcn_s_barrier(); \
    LGKM(8); \
    MFMA16(1, af1, bf0); \
    __builtin_amdgcn_s_barrier(); \
    /* p2 */ \
    RD_A4(af1, 1, 1, t_); \
    if (I2) STAGE_A((t_) + 2, 0); \
    __builtin_amdgcn_s_barrier(); \
    LGKM(4); \
    MFMA16(0, af0, bf1); \
    if (I2) { VMCNT(6); } else if (I1) { VMCNT(4); } else { VMCNT(0); } \
    __builtin_amdgcn_s_barrier(); \
    /* p3 */ \
    if (I1) { RD_A4(af0, 0, 0, (t_) + 1); RD_B4(bf0, 0, (t_) + 1); } \
    if (I2) STAGE_B((t_) + 2, 0); \
    __builtin_amdgcn_s_barrier(); \
    if (I1) { LGKM(8); } else { LGKM(0); } \
    MFMA16(1, af1, bf1); \
    __builtin_amdgcn_s_barrier(); \
} while (0)

    for (int t = 0; t < NT - 2; ++t) KTILE(t, true, true);
    KTILE(NT - 2, true, false);
    KTILE(NT - 1, false, false);

#undef KTILE
#undef RD_A4
#undef RD_B4
#undef MFMA16
#undef STAGE_A
#undef STAGE_B

    // epilogue: C/D layout col=lane&15, row=(lane>>4)*4+reg (m89-verified)
    const int cr = (lane >> 4) << 2;
    const int cc = lane & 15;
#pragma unroll
    for (int m = 0; m < 8; ++m) {
        const int row = m0 + wr * 128 + m * 16 + cr;
#pragma unroll
        for (int n = 0; n < 4; ++n) {
            const int col = n0 + wc * 64 + n * 16 + cc;
            if (OUT_BF16) {
#pragma unroll
                for (int j = 0; j < 4; ++j)
                    Cb[(size_t)(row + j) * N + col] = (bf16_t)acc[m][n][j];
            } else {
                const float bv = bias[col];
#pragma unroll
                for (int j = 0; j < 4; ++j)
                    Cf[(size_t)(row + j) * N + col] = acc[m][n][j] + bv;
            }
        }
    }
}

// ---------------- launch ----------------
extern "C" void kernel_launch(void* const* d_in, const int* in_sizes, int n_in,
                              void* d_out, int out_size, void* d_ws, size_t ws_size,
                              hipStream_t stream) {
    const float* x    = (const float*)d_in[0];
    const float* V    = (const float*)d_in[1];
    const float* U    = (const float*)d_in[2];
    const float* v2   = (const float*)d_in[3];
    const float* v1   = (const float*)d_in[4];
    const float* u2   = (const float*)d_in[5];
    const float* u1   = (const float*)d_in[6];
    const float* V_R  = (const float*)d_in[7];
    const float* U_R  = (const float*)d_in[8];
    const float* v2_R = (const float*)d_in[9];
    const float* v1_R = (const float*)d_in[10];
    const float* u2_R = (const float*)d_in[11];
    const float* u1_R = (const float*)d_in[12];
    const float* bias = (const float*)d_in[13];
    float* out = (float*)d_out;

    char* ws = (char*)d_ws;
    bf16_t* Xb   = (bf16_t*)(ws);                                  // 64 MB: [8192][4096]
    bf16_t* Vcat = (bf16_t*)(ws + (size_t)64  * 1024 * 1024);      // 16 MB: [2048][4096]
    bf16_t* Wcat = (bf16_t*)(ws + (size_t)80  * 1024 * 1024);      // 16 MB: [4096][2048]
    bf16_t* Hb   = (bf16_t*)(ws + (size_t)96  * 1024 * 1024);      // 32 MB: [8192][2048]

    (void)hipFuncSetAttribute((const void*)gemm256_kernel<DIM_S2, DIM_IN, true>,
                              hipFuncAttributeMaxDynamicSharedMemorySize, 131072);
    (void)hipFuncSetAttribute((const void*)gemm256_kernel<DIM_OUT, DIM_S2, false>,
                              hipFuncAttributeMaxDynamicSharedMemorySize, 131072);

    cast_x_kernel    <<<16384, 256, 0, stream>>>(x, Xb);
    build_vcat_kernel<<<4096, 256, 0, stream>>>(V, v2, V_R, v2_R, Vcat);
    build_wcat_kernel<<<4096, 256, 0, stream>>>(U, v1, u2, u1, U_R, v1_R, u2_R, u1_R, Wcat);

    // GEMM1: H[8192][2048] = Xb @ Vcat^T   (K=4096), grid 8x32=256
    gemm256_kernel<DIM_S2, DIM_IN, true>
        <<<(DIM_S2 / 256) * (NROWS / 256), 512, 131072, stream>>>(Xb, Vcat, Hb, nullptr, nullptr);
    // GEMM2: out[8192][4096] = Hb @ Wcat^T + bias   (K=2048), grid 16x32=512
    gemm256_kernel<DIM_OUT, DIM_S2, false>
        <<<(DIM_OUT / 256) * (NROWS / 256), 512, 131072, stream>>>(Hb, Wcat, nullptr, out, bias);
}

// Round 4
// 289.774 us; speedup vs baseline: 1.4183x; 1.0671x over previous
//
#include <hip/hip_runtime.h>
#include <hip/hip_bf16.h>
#include <stdint.h>

typedef __bf16 bf16_t;
typedef __attribute__((ext_vector_type(8))) __bf16 bf16x8;
typedef __attribute__((ext_vector_type(4))) float f32x4;

#define DIM_IN  4096
#define DIM_OUT 4096
#define DIM_S   1024
#define DIM_S2  2048
#define NROWS   8192   // B*T = 4*2048

typedef const __attribute__((address_space(1))) void gvoid_t;
typedef __attribute__((address_space(3))) void lvoid_t;

__device__ __forceinline__ float signf(float v) {
    return (v > 0.f) ? 1.f : ((v < 0.f) ? -1.f : 0.f);
}

// ---------------- prep kernels ----------------

__global__ void cast_x_kernel(const float* __restrict__ x, bf16_t* __restrict__ xb) {
    int idx = blockIdx.x * blockDim.x + threadIdx.x;
    const float4* p = reinterpret_cast<const float4*>(x) + (size_t)idx * 2;
    float4 a = p[0], b = p[1];
    bf16x8 o;
    o[0] = (bf16_t)a.x; o[1] = (bf16_t)a.y; o[2] = (bf16_t)a.z; o[3] = (bf16_t)a.w;
    o[4] = (bf16_t)b.x; o[5] = (bf16_t)b.y; o[6] = (bf16_t)b.z; o[7] = (bf16_t)b.w;
    reinterpret_cast<bf16x8*>(xb)[idx] = o;
}

__global__ void build_vcat_kernel(const float* __restrict__ V, const float* __restrict__ v2,
                                  const float* __restrict__ V_R, const float* __restrict__ v2_R,
                                  bf16_t* __restrict__ out) {
    int idx = blockIdx.x * blockDim.x + threadIdx.x;
    int s2 = idx >> 9;
    int i0 = (idx & 511) * 8;
    const float* src; const float* sc;
    if (s2 < DIM_S) { src = V   + (size_t)s2 * DIM_IN;           sc = v2;   }
    else            { src = V_R + (size_t)(s2 - DIM_S) * DIM_IN; sc = v2_R; }
    float4 a  = *reinterpret_cast<const float4*>(src + i0);
    float4 b  = *reinterpret_cast<const float4*>(src + i0 + 4);
    float4 sa = *reinterpret_cast<const float4*>(sc + i0);
    float4 sb = *reinterpret_cast<const float4*>(sc + i0 + 4);
    bf16x8 o;
    o[0] = (bf16_t)(signf(a.x) * sa.x); o[1] = (bf16_t)(signf(a.y) * sa.y);
    o[2] = (bf16_t)(signf(a.z) * sa.z); o[3] = (bf16_t)(signf(a.w) * sa.w);
    o[4] = (bf16_t)(signf(b.x) * sb.x); o[5] = (bf16_t)(signf(b.y) * sb.y);
    o[6] = (bf16_t)(signf(b.z) * sb.z); o[7] = (bf16_t)(signf(b.w) * sb.w);
    reinterpret_cast<bf16x8*>(out)[idx] = o;
}

__global__ void build_wcat_kernel(const float* __restrict__ U, const float* __restrict__ v1,
                                  const float* __restrict__ u2, const float* __restrict__ u1,
                                  const float* __restrict__ U_R, const float* __restrict__ v1_R,
                                  const float* __restrict__ u2_R, const float* __restrict__ u1_R,
                                  bf16_t* __restrict__ out) {
    int idx = blockIdx.x * blockDim.x + threadIdx.x;
    int j  = idx >> 8;
    int s0 = (idx & 255) * 8;
    const float* srcU; const float* sv1; const float* su2; float amp;
    if (s0 < DIM_S) { srcU = U   + (size_t)j * DIM_S + s0; sv1 = v1 + s0;   su2 = u2 + s0;   amp = u1[j];   }
    else { int s = s0 - DIM_S;
           srcU = U_R + (size_t)j * DIM_S + s;  sv1 = v1_R + s; su2 = u2_R + s; amp = u1_R[j]; }
    float4 a  = *reinterpret_cast<const float4*>(srcU);
    float4 b  = *reinterpret_cast<const float4*>(srcU + 4);
    float4 va = *reinterpret_cast<const float4*>(sv1);
    float4 vb = *reinterpret_cast<const float4*>(sv1 + 4);
    float4 ua = *reinterpret_cast<const float4*>(su2);
    float4 ub = *reinterpret_cast<const float4*>(su2 + 4);
    bf16x8 o;
    o[0] = (bf16_t)(amp * va.x * ua.x * signf(a.x));
    o[1] = (bf16_t)(amp * va.y * ua.y * signf(a.y));
    o[2] = (bf16_t)(amp * va.z * ua.z * signf(a.z));
    o[3] = (bf16_t)(amp * va.w * ua.w * signf(a.w));
    o[4] = (bf16_t)(amp * vb.x * ub.x * signf(b.x));
    o[5] = (bf16_t)(amp * vb.y * ub.y * signf(b.y));
    o[6] = (bf16_t)(amp * vb.z * ub.z * signf(b.z));
    o[7] = (bf16_t)(amp * vb.w * ub.w * signf(b.w));
    reinterpret_cast<bf16x8*>(out)[idx] = o;
}

// ---------------- 256x256 loose-sync GEMM: C[M][N] = A[M][K] @ B[N][K]^T ----------------
// 512 thr = 8 waves (2Mx4N), per-wave out 128x64, BK=64.
// LDS 128 KiB: A: buf*32768 + mhalf*16384 (sub-tile = [128 rows][64 cols], 16KB).
//              B at +65536, same with nhalf. Full-128B-row staging.
// Swizzle: byte ^= ((byte>>7)&7)<<4 within a sub-tile (row-keyed; read mask is
// the per-lane constant (lane&7)<<4, so bases carry the XOR and frag steps add).
// Sync: ONE vmcnt(0)+barrier per K-tile (publication of t+1's staged data).
// All other ordering is per-wave register deps (compiler lgkmcnt) + wave skew.

#define VMCNT0() do { asm volatile("s_waitcnt vmcnt(0)" ::: "memory"); \
                      __builtin_amdgcn_sched_barrier(0); } while (0)

template<int N, int K, bool OUT_BF16>
__global__ __launch_bounds__(512, 2) void gemm256_kernel(
        const bf16_t* __restrict__ A, const bf16_t* __restrict__ B,
        bf16_t* __restrict__ Cb, float* __restrict__ Cf,
        const float* __restrict__ bias) {
    extern __shared__ char lds[];
    constexpr int NT = K / 64;
    static_assert(NT >= 2, "K too small");
    const int tid  = threadIdx.x;
    const int wave = tid >> 6;
    const int lane = tid & 63;
    const int wr = wave >> 2;    // 0..1  (M-half of the block this wave computes)
    const int wc = wave & 3;     // 0..3  (64-col N slice)

    // T1: XCD-aware bijective swizzle (nwg % 8 == 0 for both GEMMs)
    const int nwg  = gridDim.x;
    const int orig = blockIdx.x;
    const int swz  = (orig & 7) * (nwg >> 3) + (orig >> 3);
    constexpr int NTX = N / 256;
    const int n0 = (swz % NTX) * 256;
    const int m0 = (swz / NTX) * 256;

    char* ldsA = lds;
    char* ldsB = lds + 65536;

    // ---- staging source pointers (pre-inverse-swizzled; LDS dest linear) ----
    // per wave-instr j: LDS off in sub-tile = j*8192 + wave*1024 (+ lane*16 by HW).
    // source row/col from lg = off ^ ((off>>7)&7)<<4  (full 128B rows preserved).
    const char* gA[2]; const char* gB[2];
#pragma unroll
    for (int j = 0; j < 2; ++j) {
        int off = j * 8192 + wave * 1024 + lane * 16;
        int lg  = off ^ (((off >> 7) & 7) << 4);
        int row = lg >> 7;          // 0..127
        int cb  = lg & 127;         // byte within 128B row
        gA[j] = (const char*)A + (size_t)(m0 + row) * (K * 2) + cb;
        gB[j] = (const char*)B + (size_t)(n0 + row) * (K * 2) + cb;
    }

#define STAGE_A(t_, mh) do { \
    int _lo = (((t_) & 1) << 15) + ((mh) << 14) + (wave << 10); \
    size_t _ga = (size_t)(mh) * (128 * K * 2) + (size_t)(t_) * 128; \
    __builtin_amdgcn_global_load_lds((gvoid_t*)(gA[0] + _ga), (lvoid_t*)(ldsA + _lo), 16, 0, 0); \
    __builtin_amdgcn_global_load_lds((gvoid_t*)(gA[1] + _ga), (lvoid_t*)(ldsA + _lo + 8192), 16, 0, 0); \
} while (0)
#define STAGE_B(t_, nh) do { \
    int _lo = (((t_) & 1) << 15) + ((nh) << 14) + (wave << 10); \
    size_t _ga = (size_t)(nh) * (128 * K * 2) + (size_t)(t_) * 128; \
    __builtin_amdgcn_global_load_lds((gvoid_t*)(gB[0] + _ga), (lvoid_t*)(ldsB + _lo), 16, 0, 0); \
    __builtin_amdgcn_global_load_lds((gvoid_t*)(gB[1] + _ga), (lvoid_t*)(ldsB + _lo + 8192), 16, 0, 0); \
} while (0)

    // ---- swizzled read bases (kk = K-half of the 64-wide tile row) ----
    const int swzmask = (lane & 7) << 4;
    int abase0, abase1, bbase0, bbase1;
    {
        int araw = (lane & 15) * 128 + ((lane >> 4) << 4);
        abase0 = (araw ^ swzmask) + (wr << 14);
        abase1 = ((araw + 64) ^ swzmask) + (wr << 14);
        int braw = ((wc & 1) * 64 + (lane & 15)) * 128 + ((lane >> 4) << 4);
        bbase0 = (braw ^ swzmask) + ((wc >> 1) << 14);
        bbase1 = ((braw + 64) ^ swzmask) + ((wc >> 1) << 14);
    }

#define RD_A4(dst, base, mg, t_) do { \
    const int _sb = (((t_) & 1) << 15) + (base); \
    _Pragma("unroll") \
    for (int mi = 0; mi < 4; ++mi) \
        dst[mi] = *(const bf16x8*)(ldsA + _sb + ((mg) * 4 + mi) * 2048); \
} while (0)
#define RD_B4(dst, base, t_) do { \
    const int _sb = (((t_) & 1) << 15) + (base); \
    _Pragma("unroll") \
    for (int ni = 0; ni < 4; ++ni) \
        dst[ni] = *(const bf16x8*)(ldsB + _sb + ni * 2048); \
} while (0)
#define MFMA16(mg, AF, BF) do { \
    __builtin_amdgcn_s_setprio(1); \
    _Pragma("unroll") \
    for (int mi = 0; mi < 4; ++mi) \
        _Pragma("unroll") \
        for (int n = 0; n < 4; ++n) \
            acc[(mg) * 4 + mi][n] = __builtin_amdgcn_mfma_f32_16x16x32_bf16( \
                AF[mi], BF[n], acc[(mg) * 4 + mi][n], 0, 0, 0); \
    __builtin_amdgcn_s_setprio(0); \
} while (0)

    f32x4 acc[8][4];
#pragma unroll
    for (int m = 0; m < 8; ++m)
#pragma unroll
        for (int n = 0; n < 4; ++n)
            acc[m][n] = (f32x4){0.f, 0.f, 0.f, 0.f};

    bf16x8 afA[4], afB[4], bf0[4], bf1[4];

    // prologue: stage all 4 sub-tiles of t=0, publish
    STAGE_A(0, 0); STAGE_A(0, 1);
    STAGE_B(0, 0); STAGE_B(0, 1);
    VMCNT0();
    __builtin_amdgcn_s_barrier();

    for (int t = 0; t < NT; ++t) {
        const bool i1 = (t + 1 < NT);
        // ph0: (mg0, kk0) — also kick off next tile's A staging
        RD_A4(afA, abase0, 0, t);
        RD_B4(bf0, bbase0, t);
        if (i1) { STAGE_A(t + 1, 0); STAGE_A(t + 1, 1); }
        MFMA16(0, afA, bf0);
        // ph1: (mg1, kk0) — next tile's B staging
        RD_A4(afB, abase0, 1, t);
        if (i1) { STAGE_B(t + 1, 0); STAGE_B(t + 1, 1); }
        MFMA16(1, afB, bf0);
        // ph2: (mg0, kk1)
        RD_A4(afA, abase1, 0, t);
        RD_B4(bf1, bbase1, t);
        MFMA16(0, afA, bf1);
        // ph3: (mg1, kk1)
        RD_A4(afB, abase1, 1, t);
        MFMA16(1, afB, bf1);
        // publication: next tile's data landed + everyone done reading buf t
        if (i1) { VMCNT0(); }
        __builtin_amdgcn_s_barrier();
    }

#undef RD_A4
#undef RD_B4
#undef MFMA16
#undef STAGE_A
#undef STAGE_B

    // epilogue: C/D layout col=lane&15, row=(lane>>4)*4+reg (m89-verified)
    const int cr = (lane >> 4) << 2;
    const int cc = lane & 15;
#pragma unroll
    for (int m = 0; m < 8; ++m) {
        const int row = m0 + wr * 128 + m * 16 + cr;
#pragma unroll
        for (int n = 0; n < 4; ++n) {
            const int col = n0 + wc * 64 + n * 16 + cc;
            if (OUT_BF16) {
#pragma unroll
                for (int j = 0; j < 4; ++j)
                    Cb[(size_t)(row + j) * N + col] = (bf16_t)acc[m][n][j];
            } else {
                const float bv = bias[col];
#pragma unroll
                for (int j = 0; j < 4; ++j)
                    Cf[(size_t)(row + j) * N + col] = acc[m][n][j] + bv;
            }
        }
    }
}

// ---------------- launch ----------------
extern "C" void kernel_launch(void* const* d_in, const int* in_sizes, int n_in,
                              void* d_out, int out_size, void* d_ws, size_t ws_size,
                              hipStream_t stream) {
    const float* x    = (const float*)d_in[0];
    const float* V    = (const float*)d_in[1];
    const float* U    = (const float*)d_in[2];
    const float* v2   = (const float*)d_in[3];
    const float* v1   = (const float*)d_in[4];
    const float* u2   = (const float*)d_in[5];
    const float* u1   = (const float*)d_in[6];
    const float* V_R  = (const float*)d_in[7];
    const float* U_R  = (const float*)d_in[8];
    const float* v2_R = (const float*)d_in[9];
    const float* v1_R = (const float*)d_in[10];
    const float* u2_R = (const float*)d_in[11];
    const float* u1_R = (const float*)d_in[12];
    const float* bias = (const float*)d_in[13];
    float* out = (float*)d_out;

    char* ws = (char*)d_ws;
    bf16_t* Xb   = (bf16_t*)(ws);                                  // 64 MB: [8192][4096]
    bf16_t* Vcat = (bf16_t*)(ws + (size_t)64  * 1024 * 1024);      // 16 MB: [2048][4096]
    bf16_t* Wcat = (bf16_t*)(ws + (size_t)80  * 1024 * 1024);      // 16 MB: [4096][2048]
    bf16_t* Hb   = (bf16_t*)(ws + (size_t)96  * 1024 * 1024);      // 32 MB: [8192][2048]

    (void)hipFuncSetAttribute((const void*)gemm256_kernel<DIM_S2, DIM_IN, true>,
                              hipFuncAttributeMaxDynamicSharedMemorySize, 131072);
    (void)hipFuncSetAttribute((const void*)gemm256_kernel<DIM_OUT, DIM_S2, false>,
                              hipFuncAttributeMaxDynamicSharedMemorySize, 131072);

    cast_x_kernel    <<<16384, 256, 0, stream>>>(x, Xb);
    build_vcat_kernel<<<4096, 256, 0, stream>>>(V, v2, V_R, v2_R, Vcat);
    build_wcat_kernel<<<4096, 256, 0, stream>>>(U, v1, u2, u1, U_R, v1_R, u2_R, u1_R, Wcat);

    // GEMM1: H[8192][2048] = Xb @ Vcat^T   (K=4096), grid 8x32=256
    gemm256_kernel<DIM_S2, DIM_IN, true>
        <<<(DIM_S2 / 256) * (NROWS / 256), 512, 131072, stream>>>(Xb, Vcat, Hb, nullptr, nullptr);
    // GEMM2: out[8192][4096] = Hb @ Wcat^T + bias   (K=2048), grid 16x32=512
    gemm256_kernel<DIM_OUT, DIM_S2, false>
        <<<(DIM_OUT / 256) * (NROWS / 256), 512, 131072, stream>>>(Hb, Wcat, nullptr, out, bias);
}